// Round 2
// baseline (1667.578 us; speedup 1.0000x reference)
//
#include <hip/hip_runtime.h>
#include <hip/hip_bf16.h>

typedef unsigned short u16;
typedef unsigned int u32;
typedef __attribute__((ext_vector_type(4))) float fx4;
typedef __attribute__((ext_vector_type(8))) __bf16 bf8;

#define NEGV -1e9f
#define SCALE_ 0.17677669529663687f

static __device__ __forceinline__ u16 f2bu(float f){
    __hip_bfloat16 h = __float2bfloat16(f);
    return *reinterpret_cast<u16*>(&h);
}
static __device__ __forceinline__ float b2f(u16 u){
    __hip_bfloat16 h;
    *reinterpret_cast<u16*>(&h) = u;
    return __bfloat162float(h);
}

// ---- K0: fp32 -> bf16 conversion (weights) ----
__global__ void f2b_kernel(const float* __restrict__ src, u16* __restrict__ dst, int n){
    int i = blockIdx.x*256 + threadIdx.x;
    if (i < n) dst[i] = f2bu(src[i]);
}

// ---- K1: roll(-3,-3) + window partition + LN1 ----
// x[64,192,56,56] f32 -> xw[200704,192] bf16, y[200704,192] bf16 (LN1 output)
__global__ __launch_bounds__(256) void partition_ln_kernel(
        const float* __restrict__ x, const float* __restrict__ g, const float* __restrict__ bta,
        u16* __restrict__ xw, u16* __restrict__ y){
    __shared__ float lds[192*57];
    const int bi = blockIdx.x;          // b*56 + i (output row)
    const int b = bi/56, i = bi%56;
    const int si = (i+3)%56;            // source row after roll
    const float* src = x + (size_t)b*602112 + (size_t)si*56;
    for (int e = threadIdx.x; e < 10752; e += 256){
        int c = e/56, j = e%56;
        lds[c*57 + j] = src[(size_t)c*3136 + j];
    }
    __syncthreads();
    const int wrow_base = (b*8 + i/7)*8;
    const int prow = (i%7)*7;
    // write xw (bf16 residual base)
    for (int e = threadIdx.x; e < 10752; e += 256){
        int j = e/192, c = e%192;       // j = output column
        int t = (wrow_base + j/7)*49 + prow + (j%7);
        xw[(size_t)t*192 + c] = f2bu(lds[c*57 + (j+3)%56]);
    }
    // LN1 per token: wave per token, lane l covers ch l, l+64, l+128
    const int wv = threadIdx.x>>6, l = threadIdx.x&63;
    for (int j = wv; j < 56; j += 4){
        const int jj = (j+3)%56;
        float v0 = lds[l*57 + jj], v1 = lds[(l+64)*57 + jj], v2 = lds[(l+128)*57 + jj];
        float s = v0+v1+v2;
        #pragma unroll
        for (int o=32;o;o>>=1) s += __shfl_xor(s, o, 64);
        const float mean = s*(1.f/192.f);
        float d0 = v0-mean, d1 = v1-mean, d2 = v2-mean;
        float qv = d0*d0 + d1*d1 + d2*d2;
        #pragma unroll
        for (int o=32;o;o>>=1) qv += __shfl_xor(qv, o, 64);
        const float rstd = rsqrtf(qv*(1.f/192.f) + 1e-5f);
        const int t = (wrow_base + j/7)*49 + prow + (j%7);
        u16* yr = y + (size_t)t*192;
        yr[l]     = f2bu(d0*rstd*g[l]     + bta[l]);
        yr[l+64]  = f2bu(d1*rstd*g[l+64]  + bta[l+64]);
        yr[l+128] = f2bu(d2*rstd*g[l+128] + bta[l+128]);
    }
}

// ---- K9: window reverse + roll(+3,+3): xw3[200704,192] f32 -> out[64,192,56,56] ----
__global__ __launch_bounds__(256) void reverse_kernel(const float* __restrict__ xw, float* __restrict__ out){
    __shared__ float lds[192*57];
    const int bi = blockIdx.x;          // b*56 + h (output row)
    const int b = bi/56, h = bi%56;
    const int i = (h+53)%56;            // source xr row
    const int wrow_base = (b*8 + i/7)*8;
    const int prow = (i%7)*7;
    for (int e = threadIdx.x; e < 10752; e += 256){
        int j = e/192, c = e%192;
        int t = (wrow_base + j/7)*49 + prow + (j%7);
        lds[c*57 + j] = xw[(size_t)t*192 + c];
    }
    __syncthreads();
    float* dst = out + (size_t)b*602112 + (size_t)h*56;
    for (int e = threadIdx.x; e < 10752; e += 256){
        int c = e/56, w = e%56;
        dst[(size_t)c*3136 + w] = lds[c*57 + (w+53)%56];
    }
}

// ---- zero-LDS GEMM: out[M,N] = epi(A[M,K]bf16 @ Bw[N,K]^T bf16) ----
// B fragments straight from global (L2-resident weights); A streamed from HBM.
// WM x WN waves; each wave: RT*16 rows x CT*16 cols. N = WN*CT*16 (compile-time).
// ACT: exact gelu. RES: += bf16 residual [M,N]. LNOUT: also emit LN(v) bf16 (needs WN==1).
// OUTBF: bf16 out else f32. HASB: bias[N] f32.
template<int WM,int WN,int RT,int CT,int K,int ACT,int RES,int LNOUT,int OUTBF,int HASB>
__global__ __launch_bounds__(WM*WN*64) void gemm_kernel(
    const u16* __restrict__ A, const u16* __restrict__ Bw,
    const float* __restrict__ bias, const u16* __restrict__ res,
    void* __restrict__ out,
    const float* __restrict__ lng, const float* __restrict__ lnb, u16* __restrict__ yout)
{
    constexpr int N = WN*CT*16;
    constexpr int BM = WM*RT*16;
    const int tid = threadIdx.x;
    const int wv = tid>>6, l = tid&63, lr = l&15, lg = l>>4;
    const int wm = wv%WM, wn = wv/WM;
    const size_t row0 = (size_t)blockIdx.x*BM + wm*(RT*16);
    const int col0 = wn*(CT*16);
    fx4 acc[RT][CT] = {};
    const u16* Abase = A + (row0 + lr)*K + lg*8;
    const u16* Bbase = Bw + (size_t)(col0 + lr)*K + lg*8;
    #pragma unroll 6
    for (int kk=0; kk<K/32; ++kk){
        bf8 af[RT];
        #pragma unroll
        for (int r=0;r<RT;r++)
            af[r] = *(const bf8*)(Abase + (size_t)(r*16)*K + kk*32);
        #pragma unroll
        for (int c=0;c<CT;c++){
            bf8 bfr = *(const bf8*)(Bbase + (size_t)(c*16)*K + kk*32);
            #pragma unroll
            for (int r=0;r<RT;r++)
                acc[r][c] = __builtin_amdgcn_mfma_f32_16x16x32_bf16(af[r], bfr, acc[r][c], 0,0,0);
        }
    }
    // epilogue
    #pragma unroll
    for (int r=0;r<RT;r++){
        float vv[CT][4];
        #pragma unroll
        for (int c=0;c<CT;c++){
            const int col = col0 + c*16 + lr;
            const float bv = HASB ? bias[col] : 0.f;
            #pragma unroll
            for (int q=0;q<4;q++){
                const size_t grow = row0 + r*16 + lg*4 + q;
                float v = acc[r][c][q] + bv;
                if (ACT) v = 0.5f*v*(1.f + erff(v*0.70710678118654752f));
                if (RES) v += b2f(res[grow*N + col]);
                if (LNOUT) vv[c][q] = v;
                if (OUTBF) ((u16*)out)[grow*N + col] = f2bu(v);
                else       ((float*)out)[grow*N + col] = v;
            }
        }
        if (LNOUT){
            #pragma unroll
            for (int q=0;q<4;q++){
                float s = 0.f;
                #pragma unroll
                for (int c=0;c<CT;c++) s += vv[c][q];
                #pragma unroll
                for (int o=8;o;o>>=1) s += __shfl_xor(s, o, 64);
                const float mean = s*(1.f/(float)N);
                float qs = 0.f;
                #pragma unroll
                for (int c=0;c<CT;c++){ float d = vv[c][q]-mean; qs += d*d; }
                #pragma unroll
                for (int o=8;o;o>>=1) qs += __shfl_xor(qs, o, 64);
                const float rstd = rsqrtf(qs*(1.f/(float)N) + 1e-5f);
                const size_t grow = row0 + r*16 + lg*4 + q;
                #pragma unroll
                for (int c=0;c<CT;c++){
                    const int col = col0 + c*16 + lr;
                    yout[grow*N + col] = f2bu((vv[c][q]-mean)*rstd*lng[col] + lnb[col]);
                }
            }
        }
    }
}

// ---- attention: one wave per (window, head) ----
__global__ __launch_bounds__(64) void attn_kernel(const u16* __restrict__ qkv,
                                                  const float* __restrict__ rel_table,
                                                  u16* __restrict__ o)
{
    __shared__ u16 pa[64*72];
    __shared__ u16 vt[32*72];
    const int bid = blockIdx.x;
    const int widx = bid/6, h = bid - widx*6;
    const int wi = widx & 63;
    const int nhi = wi>>3, nwi = wi&7;
    const int l = threadIdx.x, lr = l&15, lg = l>>4;
    const u16* base = qkv + (size_t)widx*49*576;

    bf8 qf[4], kf[4];
    #pragma unroll
    for (int t=0;t<4;t++){
        const int row = min(t*16 + lr, 48);
        qf[t] = *(const bf8*)(base + (size_t)row*576 + h*32 + lg*8);
        kf[t] = *(const bf8*)(base + (size_t)row*576 + 192 + h*32 + lg*8);
    }
    for (int e=l; e<480; e+=64){
        int d = e/15, j = 49 + (e - d*15);
        vt[d*72 + j] = 0;
    }
    for (int e=l; e<784; e+=64){
        int j = e>>4, dp = e&15;
        u32 val = *(const u32*)(base + (size_t)j*576 + 384 + h*32 + dp*2);
        vt[(dp*2)*72 + j]   = (u16)(val & 0xffffu);
        vt[(dp*2+1)*72 + j] = (u16)(val >> 16);
    }

    fx4 acc[4][4] = {};
    #pragma unroll
    for (int ti=0;ti<4;ti++)
        #pragma unroll
        for (int tj=0;tj<4;tj++)
            acc[ti][tj] = __builtin_amdgcn_mfma_f32_16x16x32_bf16(qf[ti], kf[tj], acc[ti][tj], 0,0,0);

    int jdiv[4], jmod[4], mj[4];
    #pragma unroll
    for (int tj=0;tj<4;tj++){
        const int j = tj*16 + lr;
        if (j < 49){
            const int jd = j/7, jm = j - jd*7;
            jdiv[tj]=jd; jmod[tj]=jm;
            const int gh = nhi*7 + jd, gw = nwi*7 + jm;
            mj[tj] = (gh<49?0:(gh<53?1:2))*3 + (gw<49?0:(gw<53?1:2));
        } else { jdiv[tj]=0; jmod[tj]=0; mj[tj] = -1; }
    }
    #pragma unroll
    for (int ti=0;ti<4;ti++){
        #pragma unroll
        for (int reg=0;reg<4;reg++){
            const int i = ti*16 + lg*4 + reg;
            int id=0, im=0, mi=-2;
            if (i < 49){
                id = i/7; im = i - id*7;
                const int gh = nhi*7 + id, gw = nwi*7 + im;
                mi = (gh<49?0:(gh<53?1:2))*3 + (gw<49?0:(gw<53?1:2));
            }
            #pragma unroll
            for (int tj=0;tj<4;tj++){
                const int j = tj*16 + lr;
                float lv = NEGV;
                if (i < 49 && j < 49){
                    const int ridx = (id - jdiv[tj] + 6)*13 + (im - jmod[tj] + 6);
                    lv = acc[ti][tj][reg]*SCALE_ + rel_table[ridx*6 + h]
                       + ((mi == mj[tj]) ? 0.f : NEGV);
                }
                acc[ti][tj][reg] = lv;
            }
        }
    }
    #pragma unroll
    for (int ti=0;ti<4;ti++){
        #pragma unroll
        for (int reg=0;reg<4;reg++){
            float mx = fmaxf(fmaxf(acc[ti][0][reg], acc[ti][1][reg]),
                             fmaxf(acc[ti][2][reg], acc[ti][3][reg]));
            #pragma unroll
            for (int o2=8;o2;o2>>=1) mx = fmaxf(mx, __shfl_xor(mx, o2, 64));
            float sum = 0.f;
            #pragma unroll
            for (int tj=0;tj<4;tj++){
                float p = __expf(acc[ti][tj][reg] - mx);
                acc[ti][tj][reg] = p;
                sum += p;
            }
            #pragma unroll
            for (int o2=8;o2;o2>>=1) sum += __shfl_xor(sum, o2, 64);
            const float rs = 1.f/sum;
            #pragma unroll
            for (int tj=0;tj<4;tj++) acc[ti][tj][reg] *= rs;
        }
    }
    #pragma unroll
    for (int ti=0;ti<4;ti++)
        #pragma unroll
        for (int tj=0;tj<4;tj++)
            #pragma unroll
            for (int reg=0;reg<4;reg++)
                pa[(ti*16 + lg*4 + reg)*72 + tj*16 + lr] = f2bu(acc[ti][tj][reg]);
    __syncthreads();

    fx4 oacc[4][2] = {};
    #pragma unroll
    for (int kk=0;kk<2;kk++){
        bf8 bfr[2];
        #pragma unroll
        for (int cd=0;cd<2;cd++)
            bfr[cd] = *(const bf8*)(vt + (cd*16+lr)*72 + kk*32 + lg*8);
        #pragma unroll
        for (int ti=0;ti<4;ti++){
            bf8 afr = *(const bf8*)(pa + (ti*16+lr)*72 + kk*32 + lg*8);
            #pragma unroll
            for (int cd=0;cd<2;cd++)
                oacc[ti][cd] = __builtin_amdgcn_mfma_f32_16x16x32_bf16(afr, bfr[cd], oacc[ti][cd], 0,0,0);
        }
    }
    u16* ob = o + (size_t)widx*49*192 + h*32;
    #pragma unroll
    for (int ti=0;ti<4;ti++)
        #pragma unroll
        for (int cd=0;cd<2;cd++)
            #pragma unroll
            for (int q=0;q<4;q++){
                const int i = ti*16 + lg*4 + q;
                if (i < 49) ob[(size_t)i*192 + cd*16 + lr] = f2bu(oacc[ti][cd][q]);
            }
}

extern "C" void kernel_launch(void* const* d_in, const int* in_sizes, int n_in,
                              void* d_out, int out_size, void* d_ws, size_t ws_size,
                              hipStream_t stream)
{
    const float* x      = (const float*)d_in[0];
    const float* ln1_g  = (const float*)d_in[1];
    const float* ln1_b  = (const float*)d_in[2];
    const float* qkv_w  = (const float*)d_in[3];
    const float* out_w  = (const float*)d_in[4];
    const float* out_b  = (const float*)d_in[5];
    const float* ln2_g  = (const float*)d_in[6];
    const float* ln2_b  = (const float*)d_in[7];
    const float* mlp_w1 = (const float*)d_in[8];
    const float* mlp_b1 = (const float*)d_in[9];
    const float* mlp_w2 = (const float*)d_in[10];
    const float* mlp_b2 = (const float*)d_in[11];
    const float* rel_t  = (const float*)d_in[12];

    char* ws = (char*)d_ws;
    // region 0 (154 MB): Y / O / Y2 (bf16 [T,192], first 77 MB), later xw3 f32 [T,192]
    u16*   Ybuf = (u16*)ws;
    float* OutF = (float*)ws;
    u16*   XWbuf = (u16*)(ws + 154140672);      // xw / xw2 bf16 [T,192]
    u16*   QKVH  = (u16*)(ws + 231211008);      // qkv [T,576] then h [T,768] bf16
    u16*   Wq = (u16*)(ws + 539492352);
    u16*   Wo = Wq + 110592;
    u16*   W1 = Wo + 36864;
    u16*   W2 = W1 + 147456;

    f2b_kernel<<<(110592+255)/256,256,0,stream>>>(qkv_w, Wq, 110592);
    f2b_kernel<<<(36864+255)/256,256,0,stream>>>(out_w, Wo, 36864);
    f2b_kernel<<<(147456+255)/256,256,0,stream>>>(mlp_w1, W1, 147456);
    f2b_kernel<<<(147456+255)/256,256,0,stream>>>(mlp_w2, W2, 147456);

    // partition + LN1
    partition_ln_kernel<<<3584,256,0,stream>>>(x, ln1_g, ln1_b, XWbuf, Ybuf);
    // qkv = y @ Wq^T : [T,576] bf16   (BM=32, 6 waves x 96 cols)
    gemm_kernel<1,6,2,6,192,0,0,0,1,0><<<6272,384,0,stream>>>(Ybuf, Wq, nullptr, nullptr, QKVH, nullptr, nullptr, nullptr);
    attn_kernel<<<24576,64,0,stream>>>(QKVH, rel_t, Ybuf);
    // xw2 = xw + o @ Wo^T + b (bf16, in-place XW) ; y2 = LN2(xw2) -> Ybuf (in-place over O)
    gemm_kernel<4,1,1,12,192,0,1,1,1,1><<<3136,256,0,stream>>>(Ybuf, Wo, out_b, XWbuf, XWbuf, ln2_g, ln2_b, Ybuf);
    // h = gelu(y2 @ W1^T + b1) : [T,768] bf16  (BM=32, 8 waves x 96 cols)
    gemm_kernel<1,8,2,6,192,1,0,0,1,1><<<6272,512,0,stream>>>(Ybuf, W1, mlp_b1, nullptr, QKVH, nullptr, nullptr, nullptr);
    // xw3 = xw2 + h @ W2^T + b2 : f32 -> OutF (region 0)
    gemm_kernel<4,1,1,12,768,0,1,0,0,1><<<3136,256,0,stream>>>(QKVH, W2, mlp_b2, XWbuf, OutF, nullptr, nullptr, nullptr);
    reverse_kernel<<<3584,256,0,stream>>>(OutF, (float*)d_out);
}

// Round 3
// 1189.825 us; speedup vs baseline: 1.4015x; 1.4015x over previous
//
#include <hip/hip_runtime.h>
#include <hip/hip_bf16.h>

typedef unsigned short u16;
typedef unsigned int u32;
typedef __attribute__((ext_vector_type(4))) float fx4;
typedef __attribute__((ext_vector_type(8))) __bf16 bf8;

#define NEGV -1e9f
#define SCALE_ 0.17677669529663687f

static __device__ __forceinline__ u16 f2bu(float f){
    __hip_bfloat16 h = __float2bfloat16(f);
    return *reinterpret_cast<u16*>(&h);
}
static __device__ __forceinline__ float b2f(u16 u){
    __hip_bfloat16 h;
    *reinterpret_cast<u16*>(&h) = u;
    return __bfloat162float(h);
}

// ---- K0: fp32 -> bf16 conversion of all 4 weight matrices, one launch ----
__global__ __launch_bounds__(256) void f2b4_kernel(
        const float* __restrict__ s0, const float* __restrict__ s1,
        const float* __restrict__ s2, const float* __restrict__ s3,
        u16* __restrict__ d0, u16* __restrict__ d1,
        u16* __restrict__ d2, u16* __restrict__ d3){
    int i = blockIdx.x*256 + threadIdx.x;
    if (i < 110592) d0[i] = f2bu(s0[i]);
    if (i < 36864)  d1[i] = f2bu(s1[i]);
    if (i < 147456){ d2[i] = f2bu(s2[i]); d3[i] = f2bu(s3[i]); }
}

// ---- K1: roll(-3,-3) + window partition + LN1 ----
__global__ __launch_bounds__(256) void partition_ln_kernel(
        const float* __restrict__ x, const float* __restrict__ g, const float* __restrict__ bta,
        u16* __restrict__ xw, u16* __restrict__ y){
    __shared__ float lds[192*57];
    const int bi = blockIdx.x;
    const int b = bi/56, i = bi%56;
    const int si = (i+3)%56;
    const float* src = x + (size_t)b*602112 + (size_t)si*56;
    for (int e = threadIdx.x; e < 10752; e += 256){
        int c = e/56, j = e%56;
        lds[c*57 + j] = src[(size_t)c*3136 + j];
    }
    __syncthreads();
    const int wrow_base = (b*8 + i/7)*8;
    const int prow = (i%7)*7;
    for (int e = threadIdx.x; e < 10752; e += 256){
        int j = e/192, c = e%192;
        int t = (wrow_base + j/7)*49 + prow + (j%7);
        xw[(size_t)t*192 + c] = f2bu(lds[c*57 + (j+3)%56]);
    }
    const int wv = threadIdx.x>>6, l = threadIdx.x&63;
    for (int j = wv; j < 56; j += 4){
        const int jj = (j+3)%56;
        float v0 = lds[l*57 + jj], v1 = lds[(l+64)*57 + jj], v2 = lds[(l+128)*57 + jj];
        float s = v0+v1+v2;
        #pragma unroll
        for (int o=32;o;o>>=1) s += __shfl_xor(s, o, 64);
        const float mean = s*(1.f/192.f);
        float d0 = v0-mean, d1 = v1-mean, d2 = v2-mean;
        float qv = d0*d0 + d1*d1 + d2*d2;
        #pragma unroll
        for (int o=32;o;o>>=1) qv += __shfl_xor(qv, o, 64);
        const float rstd = rsqrtf(qv*(1.f/192.f) + 1e-5f);
        const int t = (wrow_base + j/7)*49 + prow + (j%7);
        u16* yr = y + (size_t)t*192;
        yr[l]     = f2bu(d0*rstd*g[l]     + bta[l]);
        yr[l+64]  = f2bu(d1*rstd*g[l+64]  + bta[l+64]);
        yr[l+128] = f2bu(d2*rstd*g[l+128] + bta[l+128]);
    }
}

// ---- K9: window reverse + roll(+3,+3) ----
__global__ __launch_bounds__(256) void reverse_kernel(const float* __restrict__ xw, float* __restrict__ out){
    __shared__ float lds[192*57];
    const int bi = blockIdx.x;
    const int b = bi/56, h = bi%56;
    const int i = (h+53)%56;
    const int wrow_base = (b*8 + i/7)*8;
    const int prow = (i%7)*7;
    for (int e = threadIdx.x; e < 10752; e += 256){
        int j = e/192, c = e%192;
        int t = (wrow_base + j/7)*49 + prow + (j%7);
        lds[c*57 + j] = xw[(size_t)t*192 + c];
    }
    __syncthreads();
    float* dst = out + (size_t)b*602112 + (size_t)h*56;
    for (int e = threadIdx.x; e < 10752; e += 256){
        int c = e/56, w = e%56;
        dst[(size_t)c*3136 + w] = lds[c*57 + (w+53)%56];
    }
}

// ---- GEMM: B panel staged in LDS (192 cols x 96-K chunks, pitch 104),
//      A streamed from global into registers. Zero barriers inside K-loop.
//      4 waves, each wave: 32 rows x 192 cols (acc[2][12]). BM=128.
//      NC col-chunks looped INSIDE the block (A panel stays L2-hot per XCD).
// K compile-time (192 or 768). Ntot runtime stride of out/res.
template<int NC,int K,int ACT,int RES,int LNOUT,int OUTBF,int HASB>
__global__ __launch_bounds__(256) void gemm_kernel(
    const u16* __restrict__ A, const u16* __restrict__ Bw,
    const float* __restrict__ bias, const u16* __restrict__ res,
    void* __restrict__ out,
    const float* __restrict__ lng, const float* __restrict__ lnb, u16* __restrict__ yout,
    int Ntot)
{
    constexpr int NKC = K/96;
    __shared__ __align__(16) u16 Bs[192*104];
    const int tid = threadIdx.x;
    const int w = tid>>6, l = tid&63, lr = l&15, lg = l>>4;
    const size_t row0 = (size_t)blockIdx.x*128;

    for (int nc=0; nc<NC; ++nc){
        const int col0 = nc*192;
        fx4 acc[2][12] = {};
        for (int kc=0; kc<NKC; ++kc){
            __syncthreads();
            // stage B chunk: 192 rows x 96 elems (12 x 16B units per row)
            for (int u = tid; u < 2304; u += 256){
                const int n = u/12, c = u - n*12;
                uint4 v = *(const uint4*)(Bw + (size_t)(col0+n)*K + kc*96 + c*8);
                *(uint4*)(Bs + n*104 + c*8) = v;
            }
            __syncthreads();
            #pragma unroll
            for (int kk=0; kk<3; ++kk){
                const u16* Ab = A + (row0 + w*32 + lr)*K + kc*96 + kk*32 + lg*8;
                bf8 af0 = *(const bf8*)(Ab);
                bf8 af1 = *(const bf8*)(Ab + 16*K);
                #pragma unroll
                for (int c=0; c<12; ++c){
                    bf8 bfr = *(const bf8*)(Bs + (c*16+lr)*104 + kk*32 + lg*8);
                    acc[0][c] = __builtin_amdgcn_mfma_f32_16x16x32_bf16(af0, bfr, acc[0][c], 0,0,0);
                    acc[1][c] = __builtin_amdgcn_mfma_f32_16x16x32_bf16(af1, bfr, acc[1][c], 0,0,0);
                }
            }
        }
        // epilogue for this col-chunk
        #pragma unroll
        for (int r=0;r<2;r++){
            float vv[12][4];
            #pragma unroll
            for (int c=0;c<12;c++){
                const int col = col0 + c*16 + lr;
                const float bv = HASB ? bias[col] : 0.f;
                #pragma unroll
                for (int q=0;q<4;q++){
                    const size_t grow = row0 + w*32 + r*16 + lg*4 + q;
                    float v = acc[r][c][q] + bv;
                    if (ACT) v = 0.5f*v*(1.f + erff(v*0.70710678118654752f));
                    if (RES) v += b2f(res[grow*Ntot + col]);
                    vv[c][q] = v;
                    if (OUTBF) ((u16*)out)[grow*Ntot + col] = f2bu(v);
                    else       ((float*)out)[grow*Ntot + col] = v;
                }
            }
            if (LNOUT){
                #pragma unroll
                for (int q=0;q<4;q++){
                    float s = 0.f;
                    #pragma unroll
                    for (int c=0;c<12;c++) s += vv[c][q];
                    #pragma unroll
                    for (int o=8;o;o>>=1) s += __shfl_xor(s, o, 64);
                    const float mean = s*(1.f/192.f);
                    float qs = 0.f;
                    #pragma unroll
                    for (int c=0;c<12;c++){ float d = vv[c][q]-mean; qs += d*d; }
                    #pragma unroll
                    for (int o=8;o;o>>=1) qs += __shfl_xor(qs, o, 64);
                    const float rstd = rsqrtf(qs*(1.f/192.f) + 1e-5f);
                    const size_t grow = row0 + w*32 + r*16 + lg*4 + q;
                    #pragma unroll
                    for (int c=0;c<12;c++){
                        const int col = c*16 + lr;
                        yout[grow*192 + col] = f2bu((vv[c][q]-mean)*rstd*lng[col] + lnb[col]);
                    }
                }
            }
        }
    }
}

// ---- attention: one wave per (window, head) ----
__global__ __launch_bounds__(64) void attn_kernel(const u16* __restrict__ qkv,
                                                  const float* __restrict__ rel_table,
                                                  u16* __restrict__ o)
{
    __shared__ u16 pa[64*72];
    __shared__ u16 vt[32*72];
    const int bid = blockIdx.x;
    const int widx = bid/6, h = bid - widx*6;
    const int wi = widx & 63;
    const int nhi = wi>>3, nwi = wi&7;
    const int l = threadIdx.x, lr = l&15, lg = l>>4;
    const u16* base = qkv + (size_t)widx*49*576;

    bf8 qf[4], kf[4];
    #pragma unroll
    for (int t=0;t<4;t++){
        const int row = min(t*16 + lr, 48);
        qf[t] = *(const bf8*)(base + (size_t)row*576 + h*32 + lg*8);
        kf[t] = *(const bf8*)(base + (size_t)row*576 + 192 + h*32 + lg*8);
    }
    for (int e=l; e<480; e+=64){
        int d = e/15, j = 49 + (e - d*15);
        vt[d*72 + j] = 0;
    }
    for (int e=l; e<784; e+=64){
        int j = e>>4, dp = e&15;
        u32 val = *(const u32*)(base + (size_t)j*576 + 384 + h*32 + dp*2);
        vt[(dp*2)*72 + j]   = (u16)(val & 0xffffu);
        vt[(dp*2+1)*72 + j] = (u16)(val >> 16);
    }

    fx4 acc[4][4] = {};
    #pragma unroll
    for (int ti=0;ti<4;ti++)
        #pragma unroll
        for (int tj=0;tj<4;tj++)
            acc[ti][tj] = __builtin_amdgcn_mfma_f32_16x16x32_bf16(qf[ti], kf[tj], acc[ti][tj], 0,0,0);

    int jdiv[4], jmod[4], mj[4];
    #pragma unroll
    for (int tj=0;tj<4;tj++){
        const int j = tj*16 + lr;
        if (j < 49){
            const int jd = j/7, jm = j - jd*7;
            jdiv[tj]=jd; jmod[tj]=jm;
            const int gh = nhi*7 + jd, gw = nwi*7 + jm;
            mj[tj] = (gh<49?0:(gh<53?1:2))*3 + (gw<49?0:(gw<53?1:2));
        } else { jdiv[tj]=0; jmod[tj]=0; mj[tj] = -1; }
    }
    #pragma unroll
    for (int ti=0;ti<4;ti++){
        #pragma unroll
        for (int reg=0;reg<4;reg++){
            const int i = ti*16 + lg*4 + reg;
            int id=0, im=0, mi=-2;
            if (i < 49){
                id = i/7; im = i - id*7;
                const int gh = nhi*7 + id, gw = nwi*7 + im;
                mi = (gh<49?0:(gh<53?1:2))*3 + (gw<49?0:(gw<53?1:2));
            }
            #pragma unroll
            for (int tj=0;tj<4;tj++){
                const int j = tj*16 + lr;
                float lv = NEGV;
                if (i < 49 && j < 49){
                    const int ridx = (id - jdiv[tj] + 6)*13 + (im - jmod[tj] + 6);
                    lv = acc[ti][tj][reg]*SCALE_ + rel_table[ridx*6 + h]
                       + ((mi == mj[tj]) ? 0.f : NEGV);
                }
                acc[ti][tj][reg] = lv;
            }
        }
    }
    #pragma unroll
    for (int ti=0;ti<4;ti++){
        #pragma unroll
        for (int reg=0;reg<4;reg++){
            float mx = fmaxf(fmaxf(acc[ti][0][reg], acc[ti][1][reg]),
                             fmaxf(acc[ti][2][reg], acc[ti][3][reg]));
            #pragma unroll
            for (int o2=8;o2;o2>>=1) mx = fmaxf(mx, __shfl_xor(mx, o2, 64));
            float sum = 0.f;
            #pragma unroll
            for (int tj=0;tj<4;tj++){
                float p = __expf(acc[ti][tj][reg] - mx);
                acc[ti][tj][reg] = p;
                sum += p;
            }
            #pragma unroll
            for (int o2=8;o2;o2>>=1) sum += __shfl_xor(sum, o2, 64);
            const float rs = 1.f/sum;
            #pragma unroll
            for (int tj=0;tj<4;tj++) acc[ti][tj][reg] *= rs;
        }
    }
    #pragma unroll
    for (int ti=0;ti<4;ti++)
        #pragma unroll
        for (int tj=0;tj<4;tj++)
            #pragma unroll
            for (int reg=0;reg<4;reg++)
                pa[(ti*16 + lg*4 + reg)*72 + tj*16 + lr] = f2bu(acc[ti][tj][reg]);
    __syncthreads();

    fx4 oacc[4][2] = {};
    #pragma unroll
    for (int kk=0;kk<2;kk++){
        bf8 bfr[2];
        #pragma unroll
        for (int cd=0;cd<2;cd++)
            bfr[cd] = *(const bf8*)(vt + (cd*16+lr)*72 + kk*32 + lg*8);
        #pragma unroll
        for (int ti=0;ti<4;ti++){
            bf8 afr = *(const bf8*)(pa + (ti*16+lr)*72 + kk*32 + lg*8);
            #pragma unroll
            for (int cd=0;cd<2;cd++)
                oacc[ti][cd] = __builtin_amdgcn_mfma_f32_16x16x32_bf16(afr, bfr[cd], oacc[ti][cd], 0,0,0);
        }
    }
    u16* ob = o + (size_t)widx*49*192 + h*32;
    #pragma unroll
    for (int ti=0;ti<4;ti++)
        #pragma unroll
        for (int cd=0;cd<2;cd++)
            #pragma unroll
            for (int q=0;q<4;q++){
                const int i = ti*16 + lg*4 + q;
                if (i < 49) ob[(size_t)i*192 + cd*16 + lr] = f2bu(oacc[ti][cd][q]);
            }
}

extern "C" void kernel_launch(void* const* d_in, const int* in_sizes, int n_in,
                              void* d_out, int out_size, void* d_ws, size_t ws_size,
                              hipStream_t stream)
{
    const float* x      = (const float*)d_in[0];
    const float* ln1_g  = (const float*)d_in[1];
    const float* ln1_b  = (const float*)d_in[2];
    const float* qkv_w  = (const float*)d_in[3];
    const float* out_w  = (const float*)d_in[4];
    const float* out_b  = (const float*)d_in[5];
    const float* ln2_g  = (const float*)d_in[6];
    const float* ln2_b  = (const float*)d_in[7];
    const float* mlp_w1 = (const float*)d_in[8];
    const float* mlp_b1 = (const float*)d_in[9];
    const float* mlp_w2 = (const float*)d_in[10];
    const float* mlp_b2 = (const float*)d_in[11];
    const float* rel_t  = (const float*)d_in[12];

    char* ws = (char*)d_ws;
    u16*   Ybuf = (u16*)ws;                     // y / O / y2 bf16 [T,192]; later xw3 f32
    float* OutF = (float*)ws;
    u16*   XWbuf = (u16*)(ws + 154140672);      // xw / xw2 bf16 [T,192]
    u16*   QKVH  = (u16*)(ws + 231211008);      // qkv [T,576] then h [T,768] bf16
    u16*   Wq = (u16*)(ws + 539492352);
    u16*   Wo = Wq + 110592;
    u16*   W1 = Wo + 36864;
    u16*   W2 = W1 + 147456;

    f2b4_kernel<<<576,256,0,stream>>>(qkv_w, out_w, mlp_w1, mlp_w2, Wq, Wo, W1, W2);

    // partition + LN1
    partition_ln_kernel<<<3584,256,0,stream>>>(x, ln1_g, ln1_b, XWbuf, Ybuf);
    // qkv = y @ Wq^T : [T,576] bf16
    gemm_kernel<3,192,0,0,0,1,0><<<1568,256,0,stream>>>(Ybuf, Wq, nullptr, nullptr, QKVH, nullptr, nullptr, nullptr, 576);
    attn_kernel<<<24576,64,0,stream>>>(QKVH, rel_t, Ybuf);
    // xw2 = xw + O @ Wo^T + b (bf16, in-place XW); y2 = LN2(xw2) -> Ybuf
    gemm_kernel<1,192,0,1,1,1,1><<<1568,256,0,stream>>>(Ybuf, Wo, out_b, XWbuf, XWbuf, ln2_g, ln2_b, Ybuf, 192);
    // h = gelu(y2 @ W1^T + b1) : [T,768] bf16
    gemm_kernel<4,192,1,0,0,1,1><<<1568,256,0,stream>>>(Ybuf, W1, mlp_b1, nullptr, QKVH, nullptr, nullptr, nullptr, 768);
    // xw3 = xw2 + h @ W2^T + b2 : f32 -> OutF
    gemm_kernel<1,768,0,1,0,0,1><<<1568,256,0,stream>>>(QKVH, W2, mlp_b2, XWbuf, OutF, nullptr, nullptr, nullptr, 192);
    reverse_kernel<<<3584,256,0,stream>>>(OutF, (float*)d_out);
}